// Round 1
// baseline (9.722 us; speedup 1.0000x reference)
//
#include <hip/hip_runtime.h>

#define NR 24
#define NZ 512

// 2*cos(pi/12 * k) for k = 0..23 (angle deltas; the -pi offset in the
// reference cancels in differences).
__device__ __constant__ float C2[NR] = {
     2.0000000000000000f,  1.9318516525781366f,  1.7320508075688774f,
     1.4142135623730951f,  1.0000000000000000f,  0.5176380902050415f,
     0.0000000000000000f, -0.5176380902050415f, -1.0000000000000000f,
    -1.4142135623730951f, -1.7320508075688774f, -1.9318516525781366f,
    -2.0000000000000000f, -1.9318516525781366f, -1.7320508075688774f,
    -1.4142135623730951f, -1.0000000000000000f, -0.5176380902050415f,
     0.0000000000000000f,  0.5176380902050415f,  1.0000000000000000f,
     1.4142135623730951f,  1.7320508075688774f,  1.9318516525781366f
};

__global__ __launch_bounds__(256) void diam_kernel(const float* __restrict__ x,
                                                   float* __restrict__ out,
                                                   int total) {
    int o = blockIdx.x * blockDim.x + threadIdx.x;
    if (o >= total) return;

    int g = o >> 9;        // (b*nf + f), nz = 512
    int z = o & (NZ - 1);
    const float* __restrict__ base = x + (size_t)g * NR * NZ + z;

    float rad[NR];
#pragma unroll
    for (int r = 0; r < NR; ++r) {
        rad[r] = base[r * NZ];   // coalesced: consecutive z across lanes
    }

    float r2[NR];
#pragma unroll
    for (int r = 0; r < NR; ++r) {
        r2[r] = rad[r] * rad[r];
    }

    float m = 0.0f;
#pragma unroll
    for (int i = 0; i < NR; ++i) {
#pragma unroll
        for (int j = i + 1; j < NR; ++j) {
            // d2 = r_i^2 + r_j^2 - 2*cos(dtheta)*r_i*r_j
            float d2 = fmaf(-C2[j - i], rad[i] * rad[j], r2[i] + r2[j]);
            m = fmaxf(m, d2);
        }
    }

    out[o] = sqrtf(m);
}

extern "C" void kernel_launch(void* const* d_in, const int* in_sizes, int n_in,
                              void* d_out, int out_size, void* d_ws, size_t ws_size,
                              hipStream_t stream) {
    const float* x = (const float*)d_in[0];
    float* out = (float*)d_out;
    int total = out_size;                 // 16*8*512 = 65536
    int block = 256;
    int grid = (total + block - 1) / block;
    diam_kernel<<<grid, block, 0, stream>>>(x, out, total);
}

// Round 2
// 9.711 us; speedup vs baseline: 1.0012x; 1.0012x over previous
//
#include <hip/hip_runtime.h>

#define NR 24
#define NZ 512

// CC[k] = 2*cos(pi/12 * k); constexpr so fully-unrolled indexing folds to
// literals / SGPR immediates (a __constant__ array would emit s_load).
constexpr float CC[NR] = {
     2.0000000000000000f,  1.9318516525781366f,  1.7320508075688774f,
     1.4142135623730951f,  1.0000000000000000f,  0.5176380902050415f,
     0.0000000000000000f, -0.5176380902050415f, -1.0000000000000000f,
    -1.4142135623730951f, -1.7320508075688774f, -1.9318516525781366f,
    -2.0000000000000000f, -1.9318516525781366f, -1.7320508075688774f,
    -1.4142135623730951f, -1.0000000000000000f, -0.5176380902050415f,
     0.0000000000000000f,  0.5176380902050415f,  1.0000000000000000f,
     1.4142135623730951f,  1.7320508075688774f,  1.9318516525781366f
};

// Two threads per output element (adjacent lanes), split by i-parity.
// d2_ij = r_j*(r_j - c*r_i) + r_i^2  (c = 2cos(dtheta))  -> 2 FMA + max
__global__ __launch_bounds__(256) void diam_kernel(const float* __restrict__ x,
                                                   float* __restrict__ out,
                                                   int total2) {
    int t = blockIdx.x * blockDim.x + threadIdx.x;
    if (t >= total2) return;

    int o    = t >> 1;       // output index (b*nf+f)*512 + z
    int half = t & 1;        // which i-parity this lane handles
    int g = o >> 9;
    int z = o & (NZ - 1);
    const float* __restrict__ base = x + (size_t)g * NR * NZ + z;

    float rad[NR];
#pragma unroll
    for (int r = 0; r < NR; ++r) {
        rad[r] = base[r * NZ];   // lane-pairs share addresses; same cacheline
    }

    float m = 0.0f;
#pragma unroll
    for (int i = 0; i < NR - 1; ++i) {
        if ((i & 1) != half) continue;   // compile-time after unroll
        float r2i = rad[i] * rad[i];
        float mi = 0.0f;
        int j = i + 1;
#pragma unroll
        for (; j + 1 < NR; j += 2) {
            float ta  = fmaf(-CC[j - i],     rad[i], rad[j]);
            float d2a = fmaf(rad[j],     ta, r2i);
            float tb  = fmaf(-CC[j + 1 - i], rad[i], rad[j + 1]);
            float d2b = fmaf(rad[j + 1], tb, r2i);
            mi = fmaxf(mi, fmaxf(d2a, d2b));   // v_max3_f32
        }
        if (j < NR) {
            float tc  = fmaf(-CC[j - i], rad[i], rad[j]);
            float d2c = fmaf(rad[j], tc, r2i);
            mi = fmaxf(mi, d2c);
        }
        m = fmaxf(m, mi);
    }

    // combine the two i-parity halves (partner lanes are adjacent)
    m = fmaxf(m, __shfl_xor(m, 1));
    out[o] = sqrtf(m);   // both partners write the identical value
}

extern "C" void kernel_launch(void* const* d_in, const int* in_sizes, int n_in,
                              void* d_out, int out_size, void* d_ws, size_t ws_size,
                              hipStream_t stream) {
    const float* x = (const float*)d_in[0];
    float* out = (float*)d_out;
    int total2 = out_size * 2;            // 131072 threads, 2 per output
    int block = 256;
    int grid = (total2 + block - 1) / block;
    diam_kernel<<<grid, block, 0, stream>>>(x, out, total2);
}